// Round 12
// baseline (131.545 us; speedup 1.0000x reference)
//
#include <hip/hip_runtime.h>
#include <math.h>

#define LSEQ 128
#define NLL 16384      // L*L
#define NBATCH 4
#define DIM 768
#define NB 4
#define ALPHA_C 32.0f
#define MRG_C 0.05f
#define CLW_C 0.05f
#define BPB 512        // blocks per batch per table (2048/4)

__device__ __forceinline__ float wave_reduce_f(float v) {
#pragma unroll
    for (int s = 1; s < 64; s <<= 1) v += __shfl_xor(v, s);
    return v;
}

__device__ __forceinline__ float dot4(float4 a, float4 b) {
    return a.x*b.x + a.y*b.y + a.z*b.z + a.w*b.w;
}

// 16-lane x 2-row groups: per wave 4 groups x 2 rows = 8 rows. 12 k-steps of
// 64 floats; each weight ds_read_b128 feeds 2 rows (36 DS/row edge, 24 senti —
// ~40% less LDS-pipe than R5's best). All global/LDS offsets are imm-foldable.
// Reduce once per row-pair (4-stage xor); R8's batched epilogue on lanes 0-7.
// Register demand ~55 -> fits the allocator's 64-reg ceiling (no spill).
template<bool EDGE>
__device__ __forceinline__ void pass_body(
    const float* __restrict__ table, const int* __restrict__ labels,
    const int* __restrict__ attn, const float* __restrict__ prox,
    const float* __restrict__ bS, const float* __restrict__ bE,
    const int* __restrict__ tlabS, const int* __restrict__ tlabE,
    float* __restrict__ pS, float* __restrict__ pE,
    float* __restrict__ partial, const float* __restrict__ wlds,
    float* __restrict__ redw, float* __restrict__ sacc_all,
    int g, int wib, int lane, int tid)
{
    const int b = g >> 9;                // batch
    const int wave_row0 = g*32 + wib*8;  // this wave's 8 rows

    // lens[b]
    int lens_i = attn[b*LSEQ + lane] + attn[b*LSEQ + 64 + lane];
#pragma unroll
    for (int s = 1; s < 64; s <<= 1) lens_i += __shfl_xor(lens_i, s);

    // proxy inverse norms (one-time, transient regs from global)
    float pinv0, pinv1, pinv2, pinv3;
    {
        const int lo4 = lane * 4;
        float s0=0,s1=0,s2=0,s3=0;
#pragma unroll
        for (int t = 0; t < 3; ++t) {
            float4 a = *(const float4*)(prox + 0*DIM + t*256 + lo4); s0 += dot4(a,a);
            float4 bq= *(const float4*)(prox + 1*DIM + t*256 + lo4); s1 += dot4(bq,bq);
            float4 c = *(const float4*)(prox + 2*DIM + t*256 + lo4); s2 += dot4(c,c);
            float4 d = *(const float4*)(prox + 3*DIM + t*256 + lo4); s3 += dot4(d,d);
        }
        s0 = wave_reduce_f(s0); s1 = wave_reduce_f(s1);
        s2 = wave_reduce_f(s2); s3 = wave_reduce_f(s3);
        pinv0 = 1.0f / fmaxf(sqrtf(s0), 1e-12f);
        pinv1 = 1.0f / fmaxf(sqrtf(s1), 1e-12f);
        pinv2 = 1.0f / fmaxf(sqrtf(s2), 1e-12f);
        pinv3 = 1.0f / fmaxf(sqrtf(s3), 1e-12f);
    }

    const int grp = lane >> 4, sub = lane & 15;
    const float* rpA = table + (size_t)(wave_row0 + grp*2) * DIM + sub*4;
    const float* rpB = rpA + DIM;
    const float* wp  = wlds + sub*4;

    float xxA=0,dA0=0,dA1=0,dA2=0,dA3=0,dAS=0,dAE=0;
    float xxB=0,dB0=0,dB1=0,dB2=0,dB3=0,dBS=0,dBE=0;

    // ---------- hot loop: 12 k-steps, all offsets immediate ----------
#pragma unroll
    for (int k = 0; k < 12; ++k) {
        const int off = k*64;
        const float4 xA = *(const float4*)(rpA + off);
        const float4 xB = *(const float4*)(rpB + off);
        const float4 w0 = *(const float4*)(wp + 0*DIM + off);
        const float4 w1 = *(const float4*)(wp + 1*DIM + off);
        const float4 w2 = *(const float4*)(wp + 2*DIM + off);
        const float4 w3 = *(const float4*)(wp + 3*DIM + off);
        xxA += dot4(xA,xA); dA0 += dot4(xA,w0); dA1 += dot4(xA,w1);
        dA2 += dot4(xA,w2); dA3 += dot4(xA,w3);
        xxB += dot4(xB,xB); dB0 += dot4(xB,w0); dB1 += dot4(xB,w1);
        dB2 += dot4(xB,w2); dB3 += dot4(xB,w3);
        if constexpr (EDGE) {
            const float4 w4 = *(const float4*)(wp + 4*DIM + off);
            const float4 w5 = *(const float4*)(wp + 5*DIM + off);
            dAS += dot4(xA,w4); dAE += dot4(xA,w5);
            dBS += dot4(xB,w4); dBE += dot4(xB,w5);
        }
    }

    // ---------- reduce across the 16-lane group (4 stages) ----------
#pragma unroll
    for (int s = 1; s < 16; s <<= 1) {
        xxA += __shfl_xor(xxA,s); dA0 += __shfl_xor(dA0,s); dA1 += __shfl_xor(dA1,s);
        dA2 += __shfl_xor(dA2,s); dA3 += __shfl_xor(dA3,s);
        xxB += __shfl_xor(xxB,s); dB0 += __shfl_xor(dB0,s); dB1 += __shfl_xor(dB1,s);
        dB2 += __shfl_xor(dB2,s); dB3 += __shfl_xor(dB3,s);
        if constexpr (EDGE) {
            dAS += __shfl_xor(dAS,s); dAE += __shfl_xor(dAE,s);
            dBS += __shfl_xor(dBS,s); dBE += __shfl_xor(dBE,s);
        }
    }
    if (sub == 0) {   // 4 leader lanes write 2 rows each to the per-wave strip
        float* dA = redw + (grp*2)*8;
        float* dB = dA + 8;
        *(float4*)dA = make_float4(xxA,dA0,dA1,dA2);
        *(float4*)dB = make_float4(xxB,dB0,dB1,dB2);
        if constexpr (EDGE) {
            *(float2*)(dA+4) = make_float2(dA3,dAS); dA[6] = dAE;
            *(float2*)(dB+4) = make_float2(dB3,dBS); dB[6] = dBE;
        } else {
            dA[4] = dA3; dB[4] = dB3;
        }
    }
    asm volatile("s_waitcnt lgkmcnt(0)" ::: "memory");   // same-wave LDS visibility

    // ---------- cold epilogue: lanes 0..7 handle the wave's 8 rows ----------
    float Pa0=0,Pa1=0,Pa2=0,Pa3=0, Na0=0,Na1=0,Na2=0,Na3=0, Ca0=0,Ca1=0,Ca2=0,Ca3=0;
    float sBS = 0.f, sBE = 0.f;
    if (lane < 8) {
        const float* src = redw + lane*8;
        const float gxx = src[0], gd0 = src[1], gd1 = src[2], gd2 = src[3], gd3 = src[4];
        const int r = wave_row0 + lane;
        const int i = r & (NLL - 1);
        const int l = i >> 7, m = i & (LSEQ - 1);
        const bool valid = (l >= 1) && (l < lens_i - 1) && (m >= 1) && (m < lens_i - 1);
        if (valid) {
            const int lab = labels[r];
            const float xinv = 1.0f / fmaxf(sqrtf(gxx), 1e-12f);
            const float c0 = gd0 * xinv * pinv0;
            const float c1 = gd1 * xinv * pinv1;
            const float c2 = gd2 * xinv * pinv2;
            const float c3 = gd3 * xinv * pinv3;
            if (lab == 0) { Pa0 = expf(-ALPHA_C*(c0 - MRG_C)); Ca0 = 1.f; }
            else          { Na0 = expf( ALPHA_C*(c0 + MRG_C)); }
            if (lab == 1) { Pa1 = expf(-ALPHA_C*(c1 - MRG_C)); Ca1 = 1.f; }
            else          { Na1 = expf( ALPHA_C*(c1 + MRG_C)); }
            if (lab == 2) { Pa2 = expf(-ALPHA_C*(c2 - MRG_C)); Ca2 = 1.f; }
            else          { Na2 = expf( ALPHA_C*(c2 + MRG_C)); }
            if (lab == 3) { Pa3 = expf(-ALPHA_C*(c3 - MRG_C)); Ca3 = 1.f; }
            else          { Na3 = expf( ALPHA_C*(c3 + MRG_C)); }
        }
        if constexpr (EDGE) {
            const float gdS = src[5], gdE = src[6];
            const float xSl = gdS + bS[0], xEl = gdE + bE[0];
            const int ls = tlabS[r], le = tlabE[r];
            const float w = (ls >= 0) ? 1.f : 0.f;
            const float spS = fmaxf(xSl, 0.f) + log1pf(expf(-fabsf(xSl)));
            const float spE = fmaxf(xEl, 0.f) + log1pf(expf(-fabsf(xEl)));
            sBS = w * (spS - xSl * (float)ls);
            sBE = w * (spE - xEl * (float)le);
            pS[r] = w / (1.f + expf(-xSl));
            pE[r] = w / (1.f + expf(-xEl));
        }
    }
    // reduce 14 accumulators over lanes 0..7 (zeros elsewhere)
#pragma unroll
    for (int s = 1; s < 8; s <<= 1) {
        Pa0 += __shfl_xor(Pa0, s); Pa1 += __shfl_xor(Pa1, s);
        Pa2 += __shfl_xor(Pa2, s); Pa3 += __shfl_xor(Pa3, s);
        Na0 += __shfl_xor(Na0, s); Na1 += __shfl_xor(Na1, s);
        Na2 += __shfl_xor(Na2, s); Na3 += __shfl_xor(Na3, s);
        Ca0 += __shfl_xor(Ca0, s); Ca1 += __shfl_xor(Ca1, s);
        Ca2 += __shfl_xor(Ca2, s); Ca3 += __shfl_xor(Ca3, s);
        sBS += __shfl_xor(sBS, s); sBE += __shfl_xor(sBE, s);
    }
    if (lane == 0) {
        float* sp = sacc_all + wib*14;
        sp[0]=Pa0; sp[1]=Pa1; sp[2]=Pa2; sp[3]=Pa3;
        sp[4]=Na0; sp[5]=Na1; sp[6]=Na2; sp[7]=Na3;
        sp[8]=Ca0; sp[9]=Ca1; sp[10]=Ca2; sp[11]=Ca3;
        sp[12]=sBS; sp[13]=sBE;
    }
    __syncthreads();
    if (tid < 14) {
        const float s = sacc_all[0*14+tid] + sacc_all[1*14+tid]
                      + sacc_all[2*14+tid] + sacc_all[3*14+tid];
        const int blk = g & (BPB - 1);
        partial[(b * 14 + tid) * BPB + blk] = s;
    }
}

// grid 4096: tbl = bid&1 (block-uniform), g = bid>>1 in [0,2048), 32 rows/block.
__global__ __launch_bounds__(256)
void fused_pass(const float* __restrict__ tabE, const float* __restrict__ tabS,
                const int* __restrict__ labE, const int* __restrict__ labSen,
                const int* __restrict__ attn,
                const float* __restrict__ proxE, const float* __restrict__ proxSen,
                const float* __restrict__ wS, const float* __restrict__ bS,
                const float* __restrict__ wE, const float* __restrict__ bE,
                const int* __restrict__ tlabS, const int* __restrict__ tlabE,
                float* __restrict__ pS, float* __restrict__ pE,
                float* __restrict__ partE, float* __restrict__ partSen)
{
    __shared__ float wlds[6*DIM];   // proxies (+ wS,wE for edge): 18432 B
    __shared__ float red[4*64];     // per-wave strip: 8 rows x 8 vals
    __shared__ float sacc[4*14];
    const int tid = threadIdx.x, wib = tid >> 6, lane = tid & 63;
    const int tbl = blockIdx.x & 1;
    const int g = blockIdx.x >> 1;
    const bool EDGE = (tbl == 0);
    const float* prox = EDGE ? proxE : proxSen;
    const int NW = EDGE ? 6 : 4;
    for (int i2 = tid; i2 < NW*192; i2 += 256) {
        const int v = i2 / 192, e = (i2 % 192) * 4;
        const float* src = (v < 4) ? (prox + v*DIM + e) : ((v == 4) ? (wS + e) : (wE + e));
        *reinterpret_cast<float4*>(&wlds[v*DIM + e]) = *reinterpret_cast<const float4*>(src);
    }
    __syncthreads();
    if (EDGE)
        pass_body<true >(tabE, labE, attn, proxE, bS, bE, tlabS, tlabE,
                         pS, pE, partE, wlds, red + wib*64, sacc, g, wib, lane, tid);
    else
        pass_body<false>(tabS, labSen, attn, proxSen, nullptr, nullptr, nullptr, nullptr,
                         nullptr, nullptr, partSen, wlds, red + wib*64, sacc,
                         g, wib, lane, tid);
}

// 10 blocks: 0-7 = prune (exact k-th largest), 8-9 = finalize (scalar outputs).
__global__ __launch_bounds__(1024)
void tail_k(const float* __restrict__ pS, const float* __restrict__ pE,
            const int* __restrict__ attn,
            const float* __restrict__ partE, const float* __restrict__ partS,
            float* __restrict__ out)
{
    __shared__ unsigned sh[NLL];     // 64 KB (prune path)
    __shared__ int csum[16];
    __shared__ float gg[56];
    const int tid = threadIdx.x, wave = tid >> 6, lane = tid & 63;

    if (blockIdx.x >= 8) {
        const int tbl = blockIdx.x - 8;
        const float* part = (tbl == 0) ? partE : partS;
        for (int grp = wave; grp < 56; grp += 16) {
            float s = 0.f;
#pragma unroll
            for (int j = lane; j < BPB; j += 64) s += part[grp*BPB + j];
            s = wave_reduce_f(s);
            if (lane == 0) gg[grp] = s;
        }
        __syncthreads();
        if (tid == 0) {
            float tot = 0.f;
            for (int b = 0; b < NBATCH; ++b) {
                const float* G = gg + b * 14;
                int nv = 0;
                for (int c = 0; c < NB; ++c) nv += (G[8+c] > 0.f) ? 1 : 0;
                const float nvf = (float)((nv > 1) ? nv : 1);
                float pos = 0.f, neg = 0.f;
                for (int c = 0; c < NB; ++c) { pos += log1pf(G[c]); neg += log1pf(G[4+c]); }
                tot += pos / nvf + neg * 0.25f;
            }
            out[tbl] = CLW_C * tot * 0.25f;
            if (tbl == 0) {
                float bs = 0.f, be = 0.f;
                for (int b = 0; b < NBATCH; ++b) { bs += gg[b*14 + 12]; be += gg[b*14 + 13]; }
                out[2] = bs * (1.0f / 65536.0f);
                out[3] = be * (1.0f / 65536.0f);
            }
        }
        return;
    }

    const int a = blockIdx.x >> 2;   // 0 = S, 1 = E
    const int b = blockIdx.x & 3;
    const float* p = (a ? pE : pS) + (size_t)b * NLL;
    float* o = out + 4 + (size_t)a * (NBATCH * NLL) + (size_t)b * NLL;

    int asum = attn[b*LSEQ + lane] + attn[b*LSEQ + 64 + lane];
#pragma unroll
    for (int s = 1; s < 64; s <<= 1) asum += __shfl_xor(asum, s);
    const int mask_len = asum - 2;
    int k = (int)((float)mask_len * 0.3f);
    k = (k > 10) ? k : 10;
    const int ml2 = mask_len * mask_len;
    k = (k < ml2) ? k : ml2;

    for (int j = tid; j < NLL; j += 1024) sh[j] = __float_as_uint(p[j]);
    __syncthreads();

    unsigned lo = 0u, hi = 0x3F800000u;   // p in [0,1] -> bits <= 0x3F800000
    for (int it = 0; it < 32; ++it) {
        if (lo >= hi) break;                       // uniform across block
        const unsigned span = hi - lo;
        const unsigned mid = lo + (span >> 1) + (span & 1u);   // ceil midpoint, > lo
        int c = 0;
        for (int j = tid; j < NLL; j += 1024) c += (sh[j] >= mid) ? 1 : 0;
#pragma unroll
        for (int s = 1; s < 64; s <<= 1) c += __shfl_xor(c, s);
        if (lane == 0) csum[wave] = c;
        __syncthreads();
        int tot = 0;
#pragma unroll
        for (int w = 0; w < 16; ++w) tot += csum[w];
        if (tot >= k) lo = mid; else hi = mid - 1u;
        __syncthreads();
    }

    for (int j = tid; j < NLL; j += 1024) o[j] = (sh[j] >= lo) ? 1.0f : 0.0f;
}

extern "C" void kernel_launch(void* const* d_in, const int* in_sizes, int n_in,
                              void* d_out, int out_size, void* d_ws, size_t ws_size,
                              hipStream_t stream)
{
    const float* table_edge  = (const float*)d_in[0];
    const float* table_senti = (const float*)d_in[1];
    const int*   attn        = (const int*)d_in[2];
    const int*   tlabS       = (const int*)d_in[3];
    const int*   tlabE       = (const int*)d_in[4];
    const int*   lab_edge    = (const int*)d_in[5];
    const int*   lab_senti   = (const int*)d_in[6];
    const float* prox_edge   = (const float*)d_in[7];
    const float* prox_senti  = (const float*)d_in[8];
    const float* w_S         = (const float*)d_in[9];
    const float* b_S         = (const float*)d_in[10];
    const float* w_E         = (const float*)d_in[11];
    const float* b_E         = (const float*)d_in[12];

    float* out   = (float*)d_out;
    float* ws    = (float*)d_ws;
    float* pS    = ws;                      // 65536
    float* pE    = ws + 65536;              // 65536
    float* partE = ws + 131072;             // 4*14*512 = 28672
    float* partS = partE + 28672;           // 28672

    fused_pass<<<4096, 256, 0, stream>>>(table_edge, table_senti,
        lab_edge, lab_senti, attn, prox_edge, prox_senti,
        w_S, b_S, w_E, b_E, tlabS, tlabE, pS, pE, partE, partS);
    tail_k<<<10, 1024, 0, stream>>>(pS, pE, attn, partE, partS, out);
}

// Round 13
// 114.441 us; speedup vs baseline: 1.1495x; 1.1495x over previous
//
#include <hip/hip_runtime.h>
#include <math.h>

#define LSEQ 128
#define NLL 16384      // L*L
#define NBATCH 4
#define DIM 768
#define NB 4
#define ALPHA_C 32.0f
#define MRG_C 0.05f
#define CLW_C 0.05f
#define BPB 512        // blocks per batch per table (2048/4)

__device__ __forceinline__ float wave_reduce_f(float v) {
#pragma unroll
    for (int s = 1; s < 64; s <<= 1) v += __shfl_xor(v, s);
    return v;
}

__device__ __forceinline__ float dot4(float4 a, float4 b) {
    return a.x*b.x + a.y*b.y + a.z*b.z + a.w*b.w;
}

// 16-lane x 2-row groups, 8 rows/wave. 12 k-steps of 64 floats; each weight
// ds_read_b128 feeds 2 rows. #pragma unroll 2 caps live transient loads at
// ~16 VGPR; __launch_bounds__(256,3) caps allocation at ~85 VGPR ->
// ~6 waves/SIMD occupancy (R12's full unroll hit 128 VGPR / 20% occ).
template<bool EDGE>
__device__ __forceinline__ void pass_body(
    const float* __restrict__ table, const int* __restrict__ labels,
    const int* __restrict__ attn, const float* __restrict__ prox,
    const float* __restrict__ bS, const float* __restrict__ bE,
    const int* __restrict__ tlabS, const int* __restrict__ tlabE,
    float* __restrict__ pS, float* __restrict__ pE,
    float* __restrict__ partial, const float* __restrict__ wlds,
    float* __restrict__ redw, float* __restrict__ sacc_all,
    int g, int wib, int lane, int tid)
{
    const int b = g >> 9;                // batch
    const int wave_row0 = g*32 + wib*8;  // this wave's 8 rows

    // lens[b]
    int lens_i = attn[b*LSEQ + lane] + attn[b*LSEQ + 64 + lane];
#pragma unroll
    for (int s = 1; s < 64; s <<= 1) lens_i += __shfl_xor(lens_i, s);

    // proxy inverse norms (one-time, transient regs from global)
    float pinv0, pinv1, pinv2, pinv3;
    {
        const int lo4 = lane * 4;
        float s0=0,s1=0,s2=0,s3=0;
#pragma unroll
        for (int t = 0; t < 3; ++t) {
            float4 a = *(const float4*)(prox + 0*DIM + t*256 + lo4); s0 += dot4(a,a);
            float4 bq= *(const float4*)(prox + 1*DIM + t*256 + lo4); s1 += dot4(bq,bq);
            float4 c = *(const float4*)(prox + 2*DIM + t*256 + lo4); s2 += dot4(c,c);
            float4 d = *(const float4*)(prox + 3*DIM + t*256 + lo4); s3 += dot4(d,d);
        }
        s0 = wave_reduce_f(s0); s1 = wave_reduce_f(s1);
        s2 = wave_reduce_f(s2); s3 = wave_reduce_f(s3);
        pinv0 = 1.0f / fmaxf(sqrtf(s0), 1e-12f);
        pinv1 = 1.0f / fmaxf(sqrtf(s1), 1e-12f);
        pinv2 = 1.0f / fmaxf(sqrtf(s2), 1e-12f);
        pinv3 = 1.0f / fmaxf(sqrtf(s3), 1e-12f);
    }

    const int grp = lane >> 4, sub = lane & 15;
    const float* rpA = table + (size_t)(wave_row0 + grp*2) * DIM + sub*4;
    const float* rpB = rpA + DIM;
    const float* wp  = wlds + sub*4;

    float xxA=0,dA0=0,dA1=0,dA2=0,dA3=0,dAS=0,dAE=0;
    float xxB=0,dB0=0,dB1=0,dB2=0,dB3=0,dBS=0,dBE=0;

    // ---------- hot loop: 12 k-steps, unroll 2 (bounded transient regs) ----------
#pragma unroll 2
    for (int k = 0; k < 12; ++k) {
        const int off = k*64;
        const float4 xA = *(const float4*)(rpA + off);
        const float4 xB = *(const float4*)(rpB + off);
        const float4 w0 = *(const float4*)(wp + 0*DIM + off);
        const float4 w1 = *(const float4*)(wp + 1*DIM + off);
        const float4 w2 = *(const float4*)(wp + 2*DIM + off);
        const float4 w3 = *(const float4*)(wp + 3*DIM + off);
        xxA += dot4(xA,xA); dA0 += dot4(xA,w0); dA1 += dot4(xA,w1);
        dA2 += dot4(xA,w2); dA3 += dot4(xA,w3);
        xxB += dot4(xB,xB); dB0 += dot4(xB,w0); dB1 += dot4(xB,w1);
        dB2 += dot4(xB,w2); dB3 += dot4(xB,w3);
        if constexpr (EDGE) {
            const float4 w4 = *(const float4*)(wp + 4*DIM + off);
            const float4 w5 = *(const float4*)(wp + 5*DIM + off);
            dAS += dot4(xA,w4); dAE += dot4(xA,w5);
            dBS += dot4(xB,w4); dBE += dot4(xB,w5);
        }
    }

    // ---------- reduce across the 16-lane group (4 stages) ----------
#pragma unroll
    for (int s = 1; s < 16; s <<= 1) {
        xxA += __shfl_xor(xxA,s); dA0 += __shfl_xor(dA0,s); dA1 += __shfl_xor(dA1,s);
        dA2 += __shfl_xor(dA2,s); dA3 += __shfl_xor(dA3,s);
        xxB += __shfl_xor(xxB,s); dB0 += __shfl_xor(dB0,s); dB1 += __shfl_xor(dB1,s);
        dB2 += __shfl_xor(dB2,s); dB3 += __shfl_xor(dB3,s);
        if constexpr (EDGE) {
            dAS += __shfl_xor(dAS,s); dAE += __shfl_xor(dAE,s);
            dBS += __shfl_xor(dBS,s); dBE += __shfl_xor(dBE,s);
        }
    }
    if (sub == 0) {   // 4 leader lanes write 2 rows each to the per-wave strip
        float* dA = redw + (grp*2)*8;
        float* dB = dA + 8;
        *(float4*)dA = make_float4(xxA,dA0,dA1,dA2);
        *(float4*)dB = make_float4(xxB,dB0,dB1,dB2);
        if constexpr (EDGE) {
            *(float2*)(dA+4) = make_float2(dA3,dAS); dA[6] = dAE;
            *(float2*)(dB+4) = make_float2(dB3,dBS); dB[6] = dBE;
        } else {
            dA[4] = dA3; dB[4] = dB3;
        }
    }
    asm volatile("s_waitcnt lgkmcnt(0)" ::: "memory");   // same-wave LDS visibility

    // ---------- cold epilogue: lanes 0..7 handle the wave's 8 rows ----------
    float Pa0=0,Pa1=0,Pa2=0,Pa3=0, Na0=0,Na1=0,Na2=0,Na3=0, Ca0=0,Ca1=0,Ca2=0,Ca3=0;
    float sBS = 0.f, sBE = 0.f;
    if (lane < 8) {
        const float* src = redw + lane*8;
        const float gxx = src[0], gd0 = src[1], gd1 = src[2], gd2 = src[3], gd3 = src[4];
        const int r = wave_row0 + lane;
        const int i = r & (NLL - 1);
        const int l = i >> 7, m = i & (LSEQ - 1);
        const bool valid = (l >= 1) && (l < lens_i - 1) && (m >= 1) && (m < lens_i - 1);
        if (valid) {
            const int lab = labels[r];
            const float xinv = 1.0f / fmaxf(sqrtf(gxx), 1e-12f);
            const float c0 = gd0 * xinv * pinv0;
            const float c1 = gd1 * xinv * pinv1;
            const float c2 = gd2 * xinv * pinv2;
            const float c3 = gd3 * xinv * pinv3;
            if (lab == 0) { Pa0 = expf(-ALPHA_C*(c0 - MRG_C)); Ca0 = 1.f; }
            else          { Na0 = expf( ALPHA_C*(c0 + MRG_C)); }
            if (lab == 1) { Pa1 = expf(-ALPHA_C*(c1 - MRG_C)); Ca1 = 1.f; }
            else          { Na1 = expf( ALPHA_C*(c1 + MRG_C)); }
            if (lab == 2) { Pa2 = expf(-ALPHA_C*(c2 - MRG_C)); Ca2 = 1.f; }
            else          { Na2 = expf( ALPHA_C*(c2 + MRG_C)); }
            if (lab == 3) { Pa3 = expf(-ALPHA_C*(c3 - MRG_C)); Ca3 = 1.f; }
            else          { Na3 = expf( ALPHA_C*(c3 + MRG_C)); }
        }
        if constexpr (EDGE) {
            const float gdS = src[5], gdE = src[6];
            const float xSl = gdS + bS[0], xEl = gdE + bE[0];
            const int ls = tlabS[r], le = tlabE[r];
            const float w = (ls >= 0) ? 1.f : 0.f;
            const float spS = fmaxf(xSl, 0.f) + log1pf(expf(-fabsf(xSl)));
            const float spE = fmaxf(xEl, 0.f) + log1pf(expf(-fabsf(xEl)));
            sBS = w * (spS - xSl * (float)ls);
            sBE = w * (spE - xEl * (float)le);
            pS[r] = w / (1.f + expf(-xSl));
            pE[r] = w / (1.f + expf(-xEl));
        }
    }
    // reduce 14 accumulators over lanes 0..7 (zeros elsewhere)
#pragma unroll
    for (int s = 1; s < 8; s <<= 1) {
        Pa0 += __shfl_xor(Pa0, s); Pa1 += __shfl_xor(Pa1, s);
        Pa2 += __shfl_xor(Pa2, s); Pa3 += __shfl_xor(Pa3, s);
        Na0 += __shfl_xor(Na0, s); Na1 += __shfl_xor(Na1, s);
        Na2 += __shfl_xor(Na2, s); Na3 += __shfl_xor(Na3, s);
        Ca0 += __shfl_xor(Ca0, s); Ca1 += __shfl_xor(Ca1, s);
        Ca2 += __shfl_xor(Ca2, s); Ca3 += __shfl_xor(Ca3, s);
        sBS += __shfl_xor(sBS, s); sBE += __shfl_xor(sBE, s);
    }
    if (lane == 0) {
        float* sp = sacc_all + wib*14;
        sp[0]=Pa0; sp[1]=Pa1; sp[2]=Pa2; sp[3]=Pa3;
        sp[4]=Na0; sp[5]=Na1; sp[6]=Na2; sp[7]=Na3;
        sp[8]=Ca0; sp[9]=Ca1; sp[10]=Ca2; sp[11]=Ca3;
        sp[12]=sBS; sp[13]=sBE;
    }
    __syncthreads();
    if (tid < 14) {
        const float s = sacc_all[0*14+tid] + sacc_all[1*14+tid]
                      + sacc_all[2*14+tid] + sacc_all[3*14+tid];
        const int blk = g & (BPB - 1);
        partial[(b * 14 + tid) * BPB + blk] = s;
    }
}

// grid 4096: tbl = bid&1 (block-uniform), g = bid>>1 in [0,2048), 32 rows/block.
__global__ __launch_bounds__(256, 3)
void fused_pass(const float* __restrict__ tabE, const float* __restrict__ tabS,
                const int* __restrict__ labE, const int* __restrict__ labSen,
                const int* __restrict__ attn,
                const float* __restrict__ proxE, const float* __restrict__ proxSen,
                const float* __restrict__ wS, const float* __restrict__ bS,
                const float* __restrict__ wE, const float* __restrict__ bE,
                const int* __restrict__ tlabS, const int* __restrict__ tlabE,
                float* __restrict__ pS, float* __restrict__ pE,
                float* __restrict__ partE, float* __restrict__ partSen)
{
    __shared__ float wlds[6*DIM];   // proxies (+ wS,wE for edge): 18432 B
    __shared__ float red[4*64];     // per-wave strip: 8 rows x 8 vals
    __shared__ float sacc[4*14];
    const int tid = threadIdx.x, wib = tid >> 6, lane = tid & 63;
    const int tbl = blockIdx.x & 1;
    const int g = blockIdx.x >> 1;
    const bool EDGE = (tbl == 0);
    const float* prox = EDGE ? proxE : proxSen;
    const int NW = EDGE ? 6 : 4;
    for (int i2 = tid; i2 < NW*192; i2 += 256) {
        const int v = i2 / 192, e = (i2 % 192) * 4;
        const float* src = (v < 4) ? (prox + v*DIM + e) : ((v == 4) ? (wS + e) : (wE + e));
        *reinterpret_cast<float4*>(&wlds[v*DIM + e]) = *reinterpret_cast<const float4*>(src);
    }
    __syncthreads();
    if (EDGE)
        pass_body<true >(tabE, labE, attn, proxE, bS, bE, tlabS, tlabE,
                         pS, pE, partE, wlds, red + wib*64, sacc, g, wib, lane, tid);
    else
        pass_body<false>(tabS, labSen, attn, proxSen, nullptr, nullptr, nullptr, nullptr,
                         nullptr, nullptr, partSen, wlds, red + wib*64, sacc,
                         g, wib, lane, tid);
}

// 10 blocks: 0-7 = prune (exact k-th largest), 8-9 = finalize (scalar outputs).
__global__ __launch_bounds__(1024)
void tail_k(const float* __restrict__ pS, const float* __restrict__ pE,
            const int* __restrict__ attn,
            const float* __restrict__ partE, const float* __restrict__ partS,
            float* __restrict__ out)
{
    __shared__ unsigned sh[NLL];     // 64 KB (prune path)
    __shared__ int csum[16];
    __shared__ float gg[56];
    const int tid = threadIdx.x, wave = tid >> 6, lane = tid & 63;

    if (blockIdx.x >= 8) {
        const int tbl = blockIdx.x - 8;
        const float* part = (tbl == 0) ? partE : partS;
        for (int grp = wave; grp < 56; grp += 16) {
            float s = 0.f;
#pragma unroll
            for (int j = lane; j < BPB; j += 64) s += part[grp*BPB + j];
            s = wave_reduce_f(s);
            if (lane == 0) gg[grp] = s;
        }
        __syncthreads();
        if (tid == 0) {
            float tot = 0.f;
            for (int b = 0; b < NBATCH; ++b) {
                const float* G = gg + b * 14;
                int nv = 0;
                for (int c = 0; c < NB; ++c) nv += (G[8+c] > 0.f) ? 1 : 0;
                const float nvf = (float)((nv > 1) ? nv : 1);
                float pos = 0.f, neg = 0.f;
                for (int c = 0; c < NB; ++c) { pos += log1pf(G[c]); neg += log1pf(G[4+c]); }
                tot += pos / nvf + neg * 0.25f;
            }
            out[tbl] = CLW_C * tot * 0.25f;
            if (tbl == 0) {
                float bs = 0.f, be = 0.f;
                for (int b = 0; b < NBATCH; ++b) { bs += gg[b*14 + 12]; be += gg[b*14 + 13]; }
                out[2] = bs * (1.0f / 65536.0f);
                out[3] = be * (1.0f / 65536.0f);
            }
        }
        return;
    }

    const int a = blockIdx.x >> 2;   // 0 = S, 1 = E
    const int b = blockIdx.x & 3;
    const float* p = (a ? pE : pS) + (size_t)b * NLL;
    float* o = out + 4 + (size_t)a * (NBATCH * NLL) + (size_t)b * NLL;

    int asum = attn[b*LSEQ + lane] + attn[b*LSEQ + 64 + lane];
#pragma unroll
    for (int s = 1; s < 64; s <<= 1) asum += __shfl_xor(asum, s);
    const int mask_len = asum - 2;
    int k = (int)((float)mask_len * 0.3f);
    k = (k > 10) ? k : 10;
    const int ml2 = mask_len * mask_len;
    k = (k < ml2) ? k : ml2;

    for (int j = tid; j < NLL; j += 1024) sh[j] = __float_as_uint(p[j]);
    __syncthreads();

    unsigned lo = 0u, hi = 0x3F800000u;   // p in [0,1] -> bits <= 0x3F800000
    for (int it = 0; it < 32; ++it) {
        if (lo >= hi) break;                       // uniform across block
        const unsigned span = hi - lo;
        const unsigned mid = lo + (span >> 1) + (span & 1u);   // ceil midpoint, > lo
        int c = 0;
        for (int j = tid; j < NLL; j += 1024) c += (sh[j] >= mid) ? 1 : 0;
#pragma unroll
        for (int s = 1; s < 64; s <<= 1) c += __shfl_xor(c, s);
        if (lane == 0) csum[wave] = c;
        __syncthreads();
        int tot = 0;
#pragma unroll
        for (int w = 0; w < 16; ++w) tot += csum[w];
        if (tot >= k) lo = mid; else hi = mid - 1u;
        __syncthreads();
    }

    for (int j = tid; j < NLL; j += 1024) o[j] = (sh[j] >= lo) ? 1.0f : 0.0f;
}

extern "C" void kernel_launch(void* const* d_in, const int* in_sizes, int n_in,
                              void* d_out, int out_size, void* d_ws, size_t ws_size,
                              hipStream_t stream)
{
    const float* table_edge  = (const float*)d_in[0];
    const float* table_senti = (const float*)d_in[1];
    const int*   attn        = (const int*)d_in[2];
    const int*   tlabS       = (const int*)d_in[3];
    const int*   tlabE       = (const int*)d_in[4];
    const int*   lab_edge    = (const int*)d_in[5];
    const int*   lab_senti   = (const int*)d_in[6];
    const float* prox_edge   = (const float*)d_in[7];
    const float* prox_senti  = (const float*)d_in[8];
    const float* w_S         = (const float*)d_in[9];
    const float* b_S         = (const float*)d_in[10];
    const float* w_E         = (const float*)d_in[11];
    const float* b_E         = (const float*)d_in[12];

    float* out   = (float*)d_out;
    float* ws    = (float*)d_ws;
    float* pS    = ws;                      // 65536
    float* pE    = ws + 65536;              // 65536
    float* partE = ws + 131072;             // 4*14*512 = 28672
    float* partS = partE + 28672;           // 28672

    fused_pass<<<4096, 256, 0, stream>>>(table_edge, table_senti,
        lab_edge, lab_senti, attn, prox_edge, prox_senti,
        w_S, b_S, w_E, b_E, tlabS, tlabE, pS, pE, partE, partS);
    tail_k<<<10, 1024, 0, stream>>>(pS, pE, attn, partE, partS, out);
}